// Round 5
// baseline (764.233 us; speedup 1.0000x reference)
//
#include <hip/hip_runtime.h>
#include <stdint.h>
#include <stddef.h>

#define BB     16384
#define TD     768
#define ID_    1024
#define HID    1024
#define OD     1024
#define NE     8
#define CB     2048
#define CAPT   34816   // 32768 assignments + up to 8*255 pad (x256 padding)
#define GIN    1792    // TD + ID_

typedef __bf16 bf16;
typedef __bf16 bf16x4 __attribute__((ext_vector_type(4)));
typedef __bf16 bf16x8 __attribute__((ext_vector_type(8)));
typedef float  f32x4  __attribute__((ext_vector_type(4)));

struct Top2 { int e0, e1; float w0, w1; };
struct Slot2 { int p0, p1; };

__device__ __forceinline__ void gload16(void* lds, const void* g) {
#if __has_builtin(__builtin_amdgcn_global_load_lds)
  __builtin_amdgcn_global_load_lds(
      (const __attribute__((address_space(1))) void*)g,
      (__attribute__((address_space(3))) void*)lds, 16, 0, 0);
#else
  *(int4*)lds = *(const int4*)g;   // reg-staged fallback
#endif
}

// ---------------- transpose + f32->bf16 convert: src[R][C] f32 -> dst[C][R] bf16
__global__ void transpose_cvt(const float* __restrict__ src, bf16* __restrict__ dst,
                              int R, int C) {
  src += (size_t)blockIdx.z * R * C;
  dst += (size_t)blockIdx.z * R * C;
  __shared__ float tile[64][65];
  const int r0 = blockIdx.y * 64, c0 = blockIdx.x * 64;
  const int t = threadIdx.x;
#pragma unroll
  for (int i = 0; i < 16; ++i) {
    int e = i * 256 + t;
    int ii = e >> 6, jj = e & 63;
    tile[ii][jj] = src[(size_t)(r0 + ii) * C + (c0 + jj)];
  }
  __syncthreads();
#pragma unroll
  for (int i = 0; i < 16; ++i) {
    int e = i * 256 + t;
    int ii = e >> 6, jj = e & 63;
    dst[(size_t)(c0 + ii) * R + (r0 + jj)] = (bf16)tile[jj][ii];
  }
}

// ---------------- fused gating matrices in fp64, TRANSPOSED output [e][1792]
__global__ void fuse_w(const float* __restrict__ Wt, const float* __restrict__ Wi,
                       const float* __restrict__ Wg, const float* __restrict__ bt,
                       const float* __restrict__ bi, const float* __restrict__ bg,
                       double* __restrict__ WgF, double* __restrict__ bgd) {
  int o = blockIdx.x * blockDim.x + threadIdx.x;
  if (o >= (GIN + 1) * NE) return;
  int idx = o >> 3, e = o & 7;
  if (idx < TD) {
    double s = 0.0;
    for (int h = 0; h < HID; ++h)
      s += (double)Wt[(size_t)idx * HID + h] * (double)Wg[(size_t)h * NE + e];
    WgF[(size_t)e * GIN + idx] = s;
  } else if (idx < GIN) {
    int r = idx - TD;
    double s = 0.0;
    for (int h = 0; h < HID; ++h)
      s += (double)Wi[(size_t)r * HID + h] * (double)Wg[(size_t)(HID + h) * NE + e];
    WgF[(size_t)e * GIN + idx] = s;
  } else {
    double s = (double)bg[e];
    for (int h = 0; h < HID; ++h) {
      s += (double)bt[h] * (double)Wg[(size_t)h * NE + e];
      s += (double)bi[h] * (double)Wg[(size_t)(HID + h) * NE + e];
    }
    bgd[e] = s;
  }
}

// ---------------- routing pass 1: LDS-staged fp64 weights, 64 rows per block.
__global__ __launch_bounds__(1024)
void route1(const float* __restrict__ text, const float* __restrict__ image,
            const float* __restrict__ noise,
            const double* __restrict__ WgF, const double* __restrict__ bgd,
            bf16* __restrict__ text_b, bf16* __restrict__ image_b,
            Top2* __restrict__ top2, int* __restrict__ counts) {
  __shared__ double wg[NE * GIN];        // 112 KiB
  __shared__ int lcnt[NE];
  const int t = threadIdx.x;
  if (t < NE) lcnt[t] = 0;
  {
    const ulonglong2* src = (const ulonglong2*)WgF;
    ulonglong2* dst = (ulonglong2*)wg;
#pragma unroll
    for (int i = 0; i < (NE * GIN) / 2 / 1024; ++i)
      dst[i * 1024 + t] = src[i * 1024 + t];
  }
  __syncthreads();

  const int wave = t >> 6, lane = t & 63;
  const int row0 = blockIdx.x * 64;
#pragma unroll
  for (int rr = 0; rr < 4; ++rr) {
    const int row = row0 + wave + rr * 16;
    const float* tr = text + (size_t)row * TD;
    const float* ir = image + (size_t)row * ID_;
    float xv[28];
#pragma unroll
    for (int c = 0; c < 12; ++c) xv[c] = tr[lane + 64 * c];
#pragma unroll
    for (int c = 0; c < 16; ++c) xv[12 + c] = ir[lane + 64 * c];
    bf16* tb = text_b + (size_t)row * TD;
    bf16* ib = image_b + (size_t)row * ID_;
#pragma unroll
    for (int c = 0; c < 12; ++c) tb[lane + 64 * c] = (bf16)xv[c];
#pragma unroll
    for (int c = 0; c < 16; ++c) ib[lane + 64 * c] = (bf16)xv[12 + c];

    double acc[NE];
#pragma unroll
    for (int e = 0; e < NE; ++e) acc[e] = 0.0;
#pragma unroll
    for (int c = 0; c < 28; ++c) {
      const double vd = (double)xv[c];
      const int idx = lane + 64 * c;
#pragma unroll
      for (int e = 0; e < NE; ++e) acc[e] = fma(vd, wg[e * GIN + idx], acc[e]);
    }
#pragma unroll
    for (int off = 32; off > 0; off >>= 1) {
#pragma unroll
      for (int e = 0; e < NE; ++e) acc[e] += __shfl_down(acc[e], off);
    }
    if (lane == 0) {
      float nz[NE];
#pragma unroll
      for (int e = 0; e < NE; ++e)
        nz[e] = (float)(acc[e] + bgd[e]) + noise[(size_t)row * NE + e];
      int i0 = 0;
#pragma unroll
      for (int e = 1; e < NE; ++e) if (nz[e] > nz[i0]) i0 = e;
      int i1 = (i0 == 0) ? 1 : 0;
#pragma unroll
      for (int e = 0; e < NE; ++e) if (e != i0 && nz[e] > nz[i1]) i1 = e;
      float tt = expf(nz[i1] - nz[i0]);
      float w0 = 1.0f / (1.0f + tt);
      float w1 = tt / (1.0f + tt);
      Top2 rec; rec.e0 = i0; rec.e1 = i1; rec.w0 = w0; rec.w1 = w1;
      top2[row] = rec;
      atomicAdd(&lcnt[i0], 1);
      atomicAdd(&lcnt[i1], 1);
    }
  }
  __syncthreads();
  if (t < NE) atomicAdd(&counts[t], lcnt[t]);
}

// ---------------- scan: offsets (padded to x256), init pos
__global__ void scan_pad(const int* __restrict__ counts, int* __restrict__ offsets,
                         int* __restrict__ padded, int* __restrict__ pos,
                         int* __restrict__ rows_list, float* __restrict__ wgt_list) {
  __shared__ int s_off[NE], s_cnt[NE], s_pad[NE];
  if (threadIdx.x == 0) {
    int off = 0;
    for (int e = 0; e < NE; ++e) {
      int c = counts[e];
      int pd = (c + 255) & ~255;
      s_cnt[e] = c; s_pad[e] = pd; s_off[e] = off;
      offsets[e] = off; padded[e] = pd; pos[e] = off;
      off += pd;
    }
    offsets[NE] = off;
  }
  __syncthreads();
  for (int e = 0; e < NE; ++e) {
    for (int i = s_cnt[e] + threadIdx.x; i < s_pad[e]; i += blockDim.x) {
      rows_list[s_off[e] + i] = 0;
      wgt_list[s_off[e] + i] = 0.0f;
    }
  }
}

// ---------------- routing pass 2: block-aggregated scatter + slot map
__global__ void route2(const Top2* __restrict__ top2, int* __restrict__ pos,
                       int* __restrict__ rows_list, float* __restrict__ wgt_list,
                       Slot2* __restrict__ slots) {
  __shared__ int lcnt[NE], lbase[NE];
  if (threadIdx.x < NE) lcnt[threadIdx.x] = 0;
  __syncthreads();
  const int r = blockIdx.x * 256 + threadIdx.x;
  Top2 tt = top2[r];
  int s0 = atomicAdd(&lcnt[tt.e0], 1);
  int s1 = atomicAdd(&lcnt[tt.e1], 1);
  __syncthreads();
  if (threadIdx.x < NE)
    lbase[threadIdx.x] = atomicAdd(&pos[threadIdx.x], lcnt[threadIdx.x]);
  __syncthreads();
  int p0 = lbase[tt.e0] + s0;
  rows_list[p0] = r; wgt_list[p0] = tt.w0;
  int p1 = lbase[tt.e1] + s1;
  rows_list[p1] = r; wgt_list[p1] = tt.w1;
  Slot2 sl; sl.p0 = p0; sl.p1 = p1;
  slots[r] = sl;
}

// ---------------- final combine: out[row] = pair[p0] + pair[p1]
__global__ __launch_bounds__(256)
void combine(const bf16* __restrict__ pairb, const Slot2* __restrict__ slots,
             float* __restrict__ out) {
  const int row = blockIdx.x;
  const Slot2 s = slots[row];
  const int t = threadIdx.x;
  const bf16x4 a = *(const bf16x4*)(pairb + (size_t)s.p0 * OD + t * 4);
  const bf16x4 b = *(const bf16x4*)(pairb + (size_t)s.p1 * OD + t * 4);
  f32x4 r;
#pragma unroll
  for (int j = 0; j < 4; ++j) r[j] = (float)a[j] + (float)b[j];
  *(f32x4*)(out + (size_t)row * OD + t * 4) = r;
}

// ================= 256x256 8-phase bf16 MFMA GEMM (T2+T3/T4+T5) =================
// C[256x256 tile] = A[M][K] * BT[N][K]^T.  512 threads = 8 waves (2M x 4N).
// Grid: x = mblk (M tiles), y = nblk (N tiles), z = expert.
// XCD note: same-A blocks (fixed x,z; y=0..3) are 64 apart in dispatch order;
// 64 % 8 == 0 -> same XCD -> A-panel L2-shared across its 4 N-blocks.
// MODE 0: proj -> combined (bf16, +bias)
// MODE 1: expert FFN1 (gathered A rows) -> h (bf16, +b1, relu)
// MODE 2: expert FFN2 -> pairbuf (bf16, w*(acc+b2))

#define BARw  __builtin_amdgcn_s_barrier()
#define BARe  do { __builtin_amdgcn_s_barrier(); __builtin_amdgcn_sched_barrier(0); } while (0)
#define LGKM0 do { asm volatile("s_waitcnt lgkmcnt(0)" ::: "memory"); \
                   __builtin_amdgcn_sched_barrier(0); } while (0)
#define VMC8  asm volatile("s_waitcnt vmcnt(8)" ::: "memory")
#define PRIO1 __builtin_amdgcn_s_setprio(1)
#define PRIO0 __builtin_amdgcn_s_setprio(0)

#define STAGE_A(BUF, KT) do { \
  _Pragma("unroll") for (int h_ = 0; h_ < 2; ++h_) \
  _Pragma("unroll") for (int j_ = 0; j_ < 2; ++j_) \
    gload16(&As[BUF][(h_ * 1024 + j_ * 512 + t) * 8], arow[h_][j_] + (size_t)(KT) * 64); \
} while (0)

#define STAGE_B(BUF, KT) do { \
  _Pragma("unroll") for (int h_ = 0; h_ < 2; ++h_) \
  _Pragma("unroll") for (int j_ = 0; j_ < 2; ++j_) \
    gload16(&Bs[BUF][(h_ * 1024 + j_ * 512 + t) * 8], brow[h_][j_] + (size_t)(KT) * 64); \
} while (0)

#define READ_A(BUF, MH) do { \
  _Pragma("unroll") for (int mf_ = 0; mf_ < 4; ++mf_) \
  _Pragma("unroll") for (int kk_ = 0; kk_ < 2; ++kk_) \
    af[mf_][kk_] = *(const bf16x8*)(&As[BUF][(wm * 128 + (MH) * 64 + mf_ * 16 + fr) * 64 + gsw[kk_]]); \
} while (0)

#define READ_B(BUF, NH) do { \
  _Pragma("unroll") for (int nf_ = 0; nf_ < 2; ++nf_) \
  _Pragma("unroll") for (int kk_ = 0; kk_ < 2; ++kk_) \
    bfr[(NH) * 2 + nf_][kk_] = *(const bf16x8*)(&Bs[BUF][(wn * 64 + (NH) * 32 + nf_ * 16 + fr) * 64 + gsw[kk_]]); \
} while (0)

#define MFMA_Q(MH, NH) do { \
  _Pragma("unroll") for (int mf_ = 0; mf_ < 4; ++mf_) \
  _Pragma("unroll") for (int nf_ = 0; nf_ < 2; ++nf_) \
  _Pragma("unroll") for (int kk_ = 0; kk_ < 2; ++kk_) \
    acc[(MH) * 4 + mf_][(NH) * 2 + nf_] = __builtin_amdgcn_mfma_f32_16x16x32_bf16( \
        af[mf_][kk_], bfr[(NH) * 2 + nf_][kk_], acc[(MH) * 4 + mf_][(NH) * 2 + nf_], 0, 0, 0); \
} while (0)

template<int MODE>
__global__ __launch_bounds__(512, 2)
void gemm256(const bf16* __restrict__ A, const bf16* __restrict__ BT,
             const float* __restrict__ bias, bf16* __restrict__ outb,
             const int* __restrict__ rows_list, const float* __restrict__ wgt_list,
             const int* __restrict__ offsets, const int* __restrict__ padded,
             int K, int lda, int ldb, int ldout, int coloff) {
  __shared__ bf16 As[2][16384];
  __shared__ bf16 Bs[2][16384];
  const int t = threadIdx.x;
  const int lane = t & 63, w = t >> 6;
  const int wm = w >> 2, wn = w & 3;
  const int mblk = blockIdx.x, nblk = blockIdx.y;   // x = M tiles (XCD A-sharing)

  long base = 0;
  if constexpr (MODE != 0) {
    const int e = blockIdx.z;
    if (mblk * 256 >= padded[e]) return;
    base = offsets[e];
    if constexpr (MODE == 1) { BT += (size_t)e * HID * CB; bias += e * HID; }
    else                     { BT += (size_t)e * OD * HID; bias += e * OD; }
  }

  // staging source pointers: thread t covers rows (h*128 + j*64 + t>>3),
  // granule XOR-pre-swizzled at the SOURCE (LDS dest stays linear).
  const int gsrc = ((t & 7) ^ ((t >> 3) & 7)) * 8;
  const bf16* arow[2][2]; const bf16* brow[2][2];
#pragma unroll
  for (int h = 0; h < 2; ++h)
#pragma unroll
    for (int j = 0; j < 2; ++j) {
      const int rl = h * 128 + j * 64 + (t >> 3);
      long ga;
      if constexpr (MODE == 1)      ga = rows_list[base + (long)mblk * 256 + rl];
      else if constexpr (MODE == 2) ga = base + (long)mblk * 256 + rl;
      else                          ga = (long)mblk * 256 + rl;
      arow[h][j] = A + ga * lda + gsrc;
      brow[h][j] = BT + (size_t)(nblk * 256 + rl) * ldb + gsrc;
    }

  // fragment-read addressing (swizzle applied on read: row&7 == lane&7)
  const int fr = lane & 15;
  const int g_hi = lane >> 4;
  int gsw[2];
#pragma unroll
  for (int kk = 0; kk < 2; ++kk) gsw[kk] = ((kk * 4 + g_hi) ^ (lane & 7)) * 8;

  bf16x8 af[4][2];    // current A mh-half frags
  bf16x8 bfr[4][2];   // all B frags (both nh halves)
  f32x4 acc[8][4];
#pragma unroll
  for (int i = 0; i < 8; ++i)
#pragma unroll
    for (int j = 0; j < 4; ++j)
#pragma unroll
      for (int r = 0; r < 4; ++r) acc[i][j][r] = 0.0f;

  const int NT = K >> 6, NIT = NT >> 1;

  // prologue: tile0 -> buf0 (8 vmem ops), tile1 -> buf1 (8 ops)
  STAGE_B(0, 0); STAGE_A(0, 0);
  STAGE_B(1, 1); STAGE_A(1, 1);
  VMC8;             // tile0 landed (tile1's 8 still outstanding)
  BARe;

  for (int i = 0; i < NIT; ++i) {
    const int kn0 = (2 * i + 2 < NT) ? 2 * i + 2 : 0;   // clamped dummy at tail
    const int kn1 = (2 * i + 3 < NT) ? 2 * i + 3 : 1;
    // ---- q0: K-tile buf0, quadrant (mh0, nh0)
    READ_A(0, 0); READ_B(0, 0);
    BARw; LGKM0;
    PRIO1; MFMA_Q(0, 0); PRIO0;
    BARe;
    // ---- q1: (mh0, nh1)
    READ_B(0, 1);
    BARw; LGKM0;
    PRIO1; MFMA_Q(0, 1); PRIO0;
    BARe;
    // ---- q2: (mh1, nh0); B-buf0 fully consumed -> stage next B into buf0
    STAGE_B(0, kn0);
    READ_A(0, 1);
    BARw; LGKM0;
    PRIO1; MFMA_Q(1, 0); PRIO0;
    BARe;
    // ---- q3: (mh1, nh1); A-buf0 consumed -> stage next A; validate buf1
    STAGE_A(0, kn0);
    VMC8;             // prev-iter q6+q7 (tile 2i+1 -> buf1) landed
    BARw; LGKM0;
    PRIO1; MFMA_Q(1, 1); PRIO0;
    BARe;
    // ---- q4: K-tile buf1, (mh0, nh0)
    READ_A(1, 0); READ_B(1, 0);
    BARw; LGKM0;
    PRIO1; MFMA_Q(0, 0); PRIO0;
    BARe;
    // ---- q5: (mh0, nh1)
    READ_B(1, 1);
    BARw; LGKM0;
    PRIO1; MFMA_Q(0, 1); PRIO0;
    BARe;
    // ---- q6: (mh1, nh0); stage next B into buf1
    STAGE_B(1, kn1);
    READ_A(1, 1);
    BARw; LGKM0;
    PRIO1; MFMA_Q(1, 0); PRIO0;
    BARe;
    // ---- q7: (mh1, nh1); stage next A into buf1; validate buf0
    STAGE_A(1, kn1);
    VMC8;             // this-iter q2+q3 (tile 2i+2 -> buf0) landed
    BARw; LGKM0;
    PRIO1; MFMA_Q(1, 1); PRIO0;
    BARe;
  }

  // epilogue: D row = (lane>>4)*4 + r, col = lane&15
  const int row_h = (lane >> 4) * 4;
#pragma unroll
  for (int nf = 0; nf < 4; ++nf) {
    const int gcol = nblk * 256 + wn * 64 + nf * 16 + fr;
    const float bv = bias[gcol];
#pragma unroll
    for (int mf = 0; mf < 8; ++mf) {
      const int rbase = wm * 128 + mf * 16 + row_h;
#pragma unroll
      for (int r = 0; r < 4; ++r) {
        const int rit = rbase + r;
        float v = acc[mf][nf][r] + bv;
        if constexpr (MODE == 0) {
          outb[((size_t)mblk * 256 + rit) * ldout + coloff + gcol] = (bf16)v;
        } else if constexpr (MODE == 1) {
          outb[(size_t)(base + (long)mblk * 256 + rit) * ldout + gcol] =
              (bf16)fmaxf(v, 0.0f);
        } else {
          const long li = base + (long)mblk * 256 + rit;
          const float wgt = wgt_list[li];
          outb[(size_t)li * ldout + gcol] = (bf16)(wgt * v);
        }
      }
    }
  }
}

extern "C" void kernel_launch(void* const* d_in, const int* in_sizes, int n_in,
                              void* d_out, int out_size, void* d_ws, size_t ws_size,
                              hipStream_t stream) {
  const float* text  = (const float*)d_in[0];
  const float* image = (const float*)d_in[1];
  const float* noise = (const float*)d_in[2];
  const float* Wt    = (const float*)d_in[3];
  const float* bt    = (const float*)d_in[4];
  const float* Wi    = (const float*)d_in[5];
  const float* bi    = (const float*)d_in[6];
  const float* Wg    = (const float*)d_in[7];
  const float* bg    = (const float*)d_in[8];
  const float* W1    = (const float*)d_in[9];
  const float* b1    = (const float*)d_in[10];
  const float* W2    = (const float*)d_in[11];
  const float* b2    = (const float*)d_in[12];
  float* out = (float*)d_out;

  char* p = (char*)d_ws;
  auto alloc = [&](size_t bytes) {
    char* r = p; p += (bytes + 255) & ~(size_t)255; return r;
  };
  // union region: {text_b, image_b} (early) / pairbuf (late, after proj GEMMs)
  const size_t sz_text  = (size_t)BB * TD * 2;
  const size_t sz_texta = (sz_text + 255) & ~(size_t)255;
  const size_t sz_image = (size_t)BB * ID_ * 2;
  const size_t sz_pair  = (size_t)CAPT * OD * 2;
  size_t sz_u0 = sz_texta + sz_image;
  if (sz_pair > sz_u0) sz_u0 = sz_pair;
  char* u0 = alloc(sz_u0);
  bf16* text_b  = (bf16*)u0;
  bf16* image_b = (bf16*)(u0 + sz_texta);
  bf16* pairb   = (bf16*)u0;

  bf16*   WtT      = (bf16*)alloc((size_t)HID * TD * 2);
  bf16*   WiT      = (bf16*)alloc((size_t)HID * ID_ * 2);
  bf16*   W1T      = (bf16*)alloc((size_t)NE * HID * CB * 2);
  bf16*   W2T      = (bf16*)alloc((size_t)NE * OD * HID * 2);
  bf16*   combined = (bf16*)alloc((size_t)BB * CB * 2);
  bf16*   hbuf     = (bf16*)alloc((size_t)CAPT * HID * 2);
  double* WgF      = (double*)alloc((size_t)NE * GIN * 8);
  double* bgd      = (double*)alloc((size_t)NE * 8);
  Top2*   top2     = (Top2*)alloc((size_t)BB * sizeof(Top2));
  Slot2*  slots    = (Slot2*)alloc((size_t)BB * sizeof(Slot2));
  int*    counts   = (int*)alloc(NE * 4);
  int*    offsets  = (int*)alloc((NE + 1) * 4);
  int*    padded   = (int*)alloc(NE * 4);
  int*    pos      = (int*)alloc(NE * 4);
  int*    rows_list= (int*)alloc((size_t)CAPT * 4);
  float*  wgt_list = (float*)alloc((size_t)CAPT * 4);

  hipMemsetAsync(counts, 0, NE * 4, stream);

  transpose_cvt<<<dim3(HID / 64, TD / 64, 1),  256, 0, stream>>>(Wt, WtT, TD, HID);
  transpose_cvt<<<dim3(HID / 64, ID_ / 64, 1), 256, 0, stream>>>(Wi, WiT, ID_, HID);
  transpose_cvt<<<dim3(HID / 64, CB / 64, NE), 256, 0, stream>>>(W1, W1T, CB, HID);
  transpose_cvt<<<dim3(OD / 64, HID / 64, NE), 256, 0, stream>>>(W2, W2T, HID, OD);

  fuse_w<<<((GIN + 1) * NE + 255) / 256, 256, 0, stream>>>(
      Wt, Wi, Wg, bt, bi, bg, WgF, bgd);
  route1<<<BB / 64, 1024, 0, stream>>>(text, image, noise, WgF, bgd,
                                       text_b, image_b, top2, counts);
  scan_pad<<<1, 256, 0, stream>>>(counts, offsets, padded, pos, rows_list, wgt_list);
  route2<<<BB / 256, 256, 0, stream>>>(top2, pos, rows_list, wgt_list, slots);

  // proj: combined[:, :1024] = text @ Wt + bt ; combined[:, 1024:] = image @ Wi + bi
  // grid: x = mblk (64), y = nblk (4)  -> same-A blocks 64 apart -> same XCD
  gemm256<0><<<dim3(BB / 256, HID / 256, 1), 512, 0, stream>>>(
      text_b, WtT, bt, combined, nullptr, nullptr, nullptr, nullptr,
      TD, TD, TD, CB, 0);
  gemm256<0><<<dim3(BB / 256, HID / 256, 1), 512, 0, stream>>>(
      image_b, WiT, bi, combined, nullptr, nullptr, nullptr, nullptr,
      ID_, ID_, ID_, CB, HID);
  // expert FFN1 (gathered) -> h
  gemm256<1><<<dim3(64, HID / 256, NE), 512, 0, stream>>>(
      combined, W1T, b1, hbuf, rows_list, nullptr, offsets, padded,
      CB, CB, CB, HID, 0);
  // expert FFN2 -> pair buffer (plain bf16 stores)
  gemm256<2><<<dim3(64, OD / 256, NE), 512, 0, stream>>>(
      hbuf, W2T, b2, pairb, rows_list, wgt_list, offsets, padded,
      HID, HID, HID, OD, 0);
  // final: out[row] = pair[p0] + pair[p1]
  combine<<<BB, 256, 0, stream>>>(pairb, slots, out);
}

// Round 6
// 655.752 us; speedup vs baseline: 1.1654x; 1.1654x over previous
//
#include <hip/hip_runtime.h>
#include <stdint.h>
#include <stddef.h>

#define BB     16384
#define TD     768
#define ID_    1024
#define HID    1024
#define OD     1024
#define NE     8
#define CB     2048
#define CAPT   34816   // 32768 assignments + up to 8*255 pad (x256 padding)
#define GIN    1792    // TD + ID_

typedef __bf16 bf16;
typedef __bf16 bf16x4 __attribute__((ext_vector_type(4)));
typedef __bf16 bf16x8 __attribute__((ext_vector_type(8)));
typedef float  f32x4  __attribute__((ext_vector_type(4)));

struct Top2 { int e0, e1; float w0, w1; };
struct Slot2 { int p0, p1; };

__device__ __forceinline__ void gload16(void* lds, const void* g) {
#if __has_builtin(__builtin_amdgcn_global_load_lds)
  __builtin_amdgcn_global_load_lds(
      (const __attribute__((address_space(1))) void*)g,
      (__attribute__((address_space(3))) void*)lds, 16, 0, 0);
#else
  *(int4*)lds = *(const int4*)g;   // reg-staged fallback
#endif
}

// ---------------- transpose + f32->bf16 convert: src[R][C] f32 -> dst[C][R] bf16
__global__ void transpose_cvt(const float* __restrict__ src, bf16* __restrict__ dst,
                              int R, int C) {
  src += (size_t)blockIdx.z * R * C;
  dst += (size_t)blockIdx.z * R * C;
  __shared__ float tile[64][65];
  const int r0 = blockIdx.y * 64, c0 = blockIdx.x * 64;
  const int t = threadIdx.x;
#pragma unroll
  for (int i = 0; i < 16; ++i) {
    int e = i * 256 + t;
    int ii = e >> 6, jj = e & 63;
    tile[ii][jj] = src[(size_t)(r0 + ii) * C + (c0 + jj)];
  }
  __syncthreads();
#pragma unroll
  for (int i = 0; i < 16; ++i) {
    int e = i * 256 + t;
    int ii = e >> 6, jj = e & 63;
    dst[(size_t)(c0 + ii) * R + (r0 + jj)] = (bf16)tile[jj][ii];
  }
}

// ---------------- fused gating matrices in fp64, TRANSPOSED output [e][1792]
__global__ void fuse_w(const float* __restrict__ Wt, const float* __restrict__ Wi,
                       const float* __restrict__ Wg, const float* __restrict__ bt,
                       const float* __restrict__ bi, const float* __restrict__ bg,
                       double* __restrict__ WgF, double* __restrict__ bgd) {
  int o = blockIdx.x * blockDim.x + threadIdx.x;
  if (o >= (GIN + 1) * NE) return;
  int idx = o >> 3, e = o & 7;
  if (idx < TD) {
    double s = 0.0;
    for (int h = 0; h < HID; ++h)
      s += (double)Wt[(size_t)idx * HID + h] * (double)Wg[(size_t)h * NE + e];
    WgF[(size_t)e * GIN + idx] = s;
  } else if (idx < GIN) {
    int r = idx - TD;
    double s = 0.0;
    for (int h = 0; h < HID; ++h)
      s += (double)Wi[(size_t)r * HID + h] * (double)Wg[(size_t)(HID + h) * NE + e];
    WgF[(size_t)e * GIN + idx] = s;
  } else {
    double s = (double)bg[e];
    for (int h = 0; h < HID; ++h) {
      s += (double)bt[h] * (double)Wg[(size_t)h * NE + e];
      s += (double)bi[h] * (double)Wg[(size_t)(HID + h) * NE + e];
    }
    bgd[e] = s;
  }
}

// ---------------- routing pass 1: LDS-staged fp64 weights, 64 rows per block.
__global__ __launch_bounds__(1024)
void route1(const float* __restrict__ text, const float* __restrict__ image,
            const float* __restrict__ noise,
            const double* __restrict__ WgF, const double* __restrict__ bgd,
            bf16* __restrict__ text_b, bf16* __restrict__ image_b,
            Top2* __restrict__ top2, int* __restrict__ counts) {
  __shared__ double wg[NE * GIN];        // 112 KiB
  __shared__ int lcnt[NE];
  const int t = threadIdx.x;
  if (t < NE) lcnt[t] = 0;
  {
    const ulonglong2* src = (const ulonglong2*)WgF;
    ulonglong2* dst = (ulonglong2*)wg;
#pragma unroll
    for (int i = 0; i < (NE * GIN) / 2 / 1024; ++i)
      dst[i * 1024 + t] = src[i * 1024 + t];
  }
  __syncthreads();

  const int wave = t >> 6, lane = t & 63;
  const int row0 = blockIdx.x * 64;
#pragma unroll
  for (int rr = 0; rr < 4; ++rr) {
    const int row = row0 + wave + rr * 16;
    const float* tr = text + (size_t)row * TD;
    const float* ir = image + (size_t)row * ID_;
    float xv[28];
#pragma unroll
    for (int c = 0; c < 12; ++c) xv[c] = tr[lane + 64 * c];
#pragma unroll
    for (int c = 0; c < 16; ++c) xv[12 + c] = ir[lane + 64 * c];
    bf16* tb = text_b + (size_t)row * TD;
    bf16* ib = image_b + (size_t)row * ID_;
#pragma unroll
    for (int c = 0; c < 12; ++c) tb[lane + 64 * c] = (bf16)xv[c];
#pragma unroll
    for (int c = 0; c < 16; ++c) ib[lane + 64 * c] = (bf16)xv[12 + c];

    double acc[NE];
#pragma unroll
    for (int e = 0; e < NE; ++e) acc[e] = 0.0;
#pragma unroll
    for (int c = 0; c < 28; ++c) {
      const double vd = (double)xv[c];
      const int idx = lane + 64 * c;
#pragma unroll
      for (int e = 0; e < NE; ++e) acc[e] = fma(vd, wg[e * GIN + idx], acc[e]);
    }
#pragma unroll
    for (int off = 32; off > 0; off >>= 1) {
#pragma unroll
      for (int e = 0; e < NE; ++e) acc[e] += __shfl_down(acc[e], off);
    }
    if (lane == 0) {
      float nz[NE];
#pragma unroll
      for (int e = 0; e < NE; ++e)
        nz[e] = (float)(acc[e] + bgd[e]) + noise[(size_t)row * NE + e];
      int i0 = 0;
#pragma unroll
      for (int e = 1; e < NE; ++e) if (nz[e] > nz[i0]) i0 = e;
      int i1 = (i0 == 0) ? 1 : 0;
#pragma unroll
      for (int e = 0; e < NE; ++e) if (e != i0 && nz[e] > nz[i1]) i1 = e;
      float tt = expf(nz[i1] - nz[i0]);
      float w0 = 1.0f / (1.0f + tt);
      float w1 = tt / (1.0f + tt);
      Top2 rec; rec.e0 = i0; rec.e1 = i1; rec.w0 = w0; rec.w1 = w1;
      top2[row] = rec;
      atomicAdd(&lcnt[i0], 1);
      atomicAdd(&lcnt[i1], 1);
    }
  }
  __syncthreads();
  if (t < NE) atomicAdd(&counts[t], lcnt[t]);
}

// ---------------- scan: offsets (padded to x256), init pos
__global__ void scan_pad(const int* __restrict__ counts, int* __restrict__ offsets,
                         int* __restrict__ padded, int* __restrict__ pos,
                         int* __restrict__ rows_list, float* __restrict__ wgt_list) {
  __shared__ int s_off[NE], s_cnt[NE], s_pad[NE];
  if (threadIdx.x == 0) {
    int off = 0;
    for (int e = 0; e < NE; ++e) {
      int c = counts[e];
      int pd = (c + 255) & ~255;
      s_cnt[e] = c; s_pad[e] = pd; s_off[e] = off;
      offsets[e] = off; padded[e] = pd; pos[e] = off;
      off += pd;
    }
    offsets[NE] = off;
  }
  __syncthreads();
  for (int e = 0; e < NE; ++e) {
    for (int i = s_cnt[e] + threadIdx.x; i < s_pad[e]; i += blockDim.x) {
      rows_list[s_off[e] + i] = 0;
      wgt_list[s_off[e] + i] = 0.0f;
    }
  }
}

// ---------------- routing pass 2: block-aggregated scatter + slot map
__global__ void route2(const Top2* __restrict__ top2, int* __restrict__ pos,
                       int* __restrict__ rows_list, float* __restrict__ wgt_list,
                       Slot2* __restrict__ slots) {
  __shared__ int lcnt[NE], lbase[NE];
  if (threadIdx.x < NE) lcnt[threadIdx.x] = 0;
  __syncthreads();
  const int r = blockIdx.x * 256 + threadIdx.x;
  Top2 tt = top2[r];
  int s0 = atomicAdd(&lcnt[tt.e0], 1);
  int s1 = atomicAdd(&lcnt[tt.e1], 1);
  __syncthreads();
  if (threadIdx.x < NE)
    lbase[threadIdx.x] = atomicAdd(&pos[threadIdx.x], lcnt[threadIdx.x]);
  __syncthreads();
  int p0 = lbase[tt.e0] + s0;
  rows_list[p0] = r; wgt_list[p0] = tt.w0;
  int p1 = lbase[tt.e1] + s1;
  rows_list[p1] = r; wgt_list[p1] = tt.w1;
  Slot2 sl; sl.p0 = p0; sl.p1 = p1;
  slots[r] = sl;
}

// ---------------- final combine: out[row] = pair[p0] + pair[p1]
__global__ __launch_bounds__(256)
void combine(const bf16* __restrict__ pairb, const Slot2* __restrict__ slots,
             float* __restrict__ out) {
  const int row = blockIdx.x;
  const Slot2 s = slots[row];
  const int t = threadIdx.x;
  const bf16x4 a = *(const bf16x4*)(pairb + (size_t)s.p0 * OD + t * 4);
  const bf16x4 b = *(const bf16x4*)(pairb + (size_t)s.p1 * OD + t * 4);
  f32x4 r;
#pragma unroll
  for (int j = 0; j < 4; ++j) r[j] = (float)a[j] + (float)b[j];
  *(f32x4*)(out + (size_t)row * OD + t * 4) = r;
}

// ================= 256x256 8-phase bf16 MFMA GEMM + 1-phase ds_read read-ahead ====
// C[256x256 tile] = A[M][K] * BT[N][K]^T.  512 threads = 8 waves (2M x 4N).
// Grid (round-4 proven order): x = nblk, y = mblk, z = expert.
// Phase P issues phase P+1's ds_reads BETWEEN its lgkmcnt(0) and its MFMA cluster,
// so the LDS port drains the next burst underneath the current MFMA cluster.
// A-fragments are double-buffered in registers (af[2][..]) to avoid reg WAR.
// MODE 0: proj -> combined (bf16, +bias)
// MODE 1: expert FFN1 (gathered A rows) -> h (bf16, +b1, relu)
// MODE 2: expert FFN2 -> pairbuf (bf16, w*(acc+b2))

#define BARw  __builtin_amdgcn_s_barrier()
#define BARe  do { __builtin_amdgcn_s_barrier(); __builtin_amdgcn_sched_barrier(0); } while (0)
#define LGKM0 do { asm volatile("s_waitcnt lgkmcnt(0)" ::: "memory"); \
                   __builtin_amdgcn_sched_barrier(0); } while (0)
#define VMC8  asm volatile("s_waitcnt vmcnt(8)" ::: "memory")
#define PRIO1 __builtin_amdgcn_s_setprio(1)
#define PRIO0 __builtin_amdgcn_s_setprio(0)

#define STAGE_A(BUF, KT) do { \
  _Pragma("unroll") for (int h_ = 0; h_ < 2; ++h_) \
  _Pragma("unroll") for (int j_ = 0; j_ < 2; ++j_) \
    gload16(&As[BUF][(h_ * 1024 + j_ * 512 + t) * 8], arow[h_][j_] + (size_t)(KT) * 64); \
} while (0)

#define STAGE_B(BUF, KT) do { \
  _Pragma("unroll") for (int h_ = 0; h_ < 2; ++h_) \
  _Pragma("unroll") for (int j_ = 0; j_ < 2; ++j_) \
    gload16(&Bs[BUF][(h_ * 1024 + j_ * 512 + t) * 8], brow[h_][j_] + (size_t)(KT) * 64); \
} while (0)

// READ_A(BUF, MH): fills af[MH]; READ_B(BUF, NH): fills bfr[NH*2+...]
#define READ_A(BUF, MH) do { \
  _Pragma("unroll") for (int mf_ = 0; mf_ < 4; ++mf_) \
  _Pragma("unroll") for (int kk_ = 0; kk_ < 2; ++kk_) \
    af[MH][mf_][kk_] = *(const bf16x8*)(&As[BUF][(wm * 128 + (MH) * 64 + mf_ * 16 + fr) * 64 + gsw[kk_]]); \
} while (0)

#define READ_B(BUF, NH) do { \
  _Pragma("unroll") for (int nf_ = 0; nf_ < 2; ++nf_) \
  _Pragma("unroll") for (int kk_ = 0; kk_ < 2; ++kk_) \
    bfr[(NH) * 2 + nf_][kk_] = *(const bf16x8*)(&Bs[BUF][(wn * 64 + (NH) * 32 + nf_ * 16 + fr) * 64 + gsw[kk_]]); \
} while (0)

#define MFMA_Q(MH, NH) do { \
  _Pragma("unroll") for (int mf_ = 0; mf_ < 4; ++mf_) \
  _Pragma("unroll") for (int nf_ = 0; nf_ < 2; ++nf_) \
  _Pragma("unroll") for (int kk_ = 0; kk_ < 2; ++kk_) \
    acc[(MH) * 4 + mf_][(NH) * 2 + nf_] = __builtin_amdgcn_mfma_f32_16x16x32_bf16( \
        af[MH][mf_][kk_], bfr[(NH) * 2 + nf_][kk_], acc[(MH) * 4 + mf_][(NH) * 2 + nf_], 0, 0, 0); \
} while (0)

template<int MODE>
__global__ __launch_bounds__(512, 2)
void gemm256(const bf16* __restrict__ A, const bf16* __restrict__ BT,
             const float* __restrict__ bias, bf16* __restrict__ outb,
             const int* __restrict__ rows_list, const float* __restrict__ wgt_list,
             const int* __restrict__ offsets, const int* __restrict__ padded,
             int K, int lda, int ldb, int ldout, int coloff) {
  __shared__ bf16 As[2][16384];
  __shared__ bf16 Bs[2][16384];
  const int t = threadIdx.x;
  const int lane = t & 63, w = t >> 6;
  const int wm = w >> 2, wn = w & 3;
  const int mblk = blockIdx.y, nblk = blockIdx.x;   // round-4 proven order

  long base = 0;
  if constexpr (MODE != 0) {
    const int e = blockIdx.z;
    if (mblk * 256 >= padded[e]) return;
    base = offsets[e];
    if constexpr (MODE == 1) { BT += (size_t)e * HID * CB; bias += e * HID; }
    else                     { BT += (size_t)e * OD * HID; bias += e * OD; }
  }

  // staging source pointers: thread t covers rows (h*128 + j*64 + t>>3),
  // granule XOR-pre-swizzled at the SOURCE (LDS dest stays linear).
  const int gsrc = ((t & 7) ^ ((t >> 3) & 7)) * 8;
  const bf16* arow[2][2]; const bf16* brow[2][2];
#pragma unroll
  for (int h = 0; h < 2; ++h)
#pragma unroll
    for (int j = 0; j < 2; ++j) {
      const int rl = h * 128 + j * 64 + (t >> 3);
      long ga;
      if constexpr (MODE == 1)      ga = rows_list[base + (long)mblk * 256 + rl];
      else if constexpr (MODE == 2) ga = base + (long)mblk * 256 + rl;
      else                          ga = (long)mblk * 256 + rl;
      arow[h][j] = A + ga * lda + gsrc;
      brow[h][j] = BT + (size_t)(nblk * 256 + rl) * ldb + gsrc;
    }

  // fragment-read addressing (swizzle applied on read: row&7 == lane&7)
  const int fr = lane & 15;
  const int g_hi = lane >> 4;
  int gsw[2];
#pragma unroll
  for (int kk = 0; kk < 2; ++kk) gsw[kk] = ((kk * 4 + g_hi) ^ (lane & 7)) * 8;

  bf16x8 af[2][4][2];   // A frags, double-buffered by mh (read-ahead WAR safety)
  bf16x8 bfr[4][2];     // B frags (both nh halves)
  f32x4 acc[8][4];
#pragma unroll
  for (int i = 0; i < 8; ++i)
#pragma unroll
    for (int j = 0; j < 4; ++j)
#pragma unroll
      for (int r = 0; r < 4; ++r) acc[i][j][r] = 0.0f;

  const int NT = K >> 6, NIT = NT >> 1;

  // prologue: tile0 -> buf0 (8 vmem ops), tile1 -> buf1 (8 ops)
  STAGE_B(0, 0); STAGE_A(0, 0);
  STAGE_B(1, 1); STAGE_A(1, 1);
  VMC8;             // tile0 landed (tile1's 8 still outstanding)
  BARe;
  READ_A(0, 0); READ_B(0, 0);   // q0's operands (buf0 landed)

  for (int i = 0; i < NIT; ++i) {
    const int kn0 = (2 * i + 2 < NT) ? 2 * i + 2 : 0;   // clamped dummy at tail
    const int kn1 = (2 * i + 3 < NT) ? 2 * i + 3 : 1;
    // ---- q0: buf0 (mh0, nh0); read-ahead q1's B
    BARw; LGKM0;
    READ_B(0, 1);
    PRIO1; MFMA_Q(0, 0); PRIO0;
    BARe;
    // ---- q1: (mh0, nh1); read-ahead q2's A (af[1])
    BARw; LGKM0;
    READ_A(0, 1);
    PRIO1; MFMA_Q(0, 1); PRIO0;
    BARe;
    // ---- q2: (mh1, nh0); B-buf0 fully consumed -> stage next B into buf0
    STAGE_B(0, kn0);
    BARw; LGKM0;
    PRIO1; MFMA_Q(1, 0); PRIO0;
    BARe;
    // ---- q3: (mh1, nh1); stage next A into buf0; land buf1; read-ahead q4 (buf1)
    STAGE_A(0, kn0);
    VMC8;             // prev-iter q6+q7 (tile 2i+1 -> buf1) landed
    BARw; LGKM0;
    READ_A(1, 0); READ_B(1, 0);
    PRIO1; MFMA_Q(1, 1); PRIO0;
    BARe;
    // ---- q4: buf1 (mh0, nh0); read-ahead q5's B
    BARw; LGKM0;
    READ_B(1, 1);
    PRIO1; MFMA_Q(0, 0); PRIO0;
    BARe;
    // ---- q5: (mh0, nh1); read-ahead q6's A
    BARw; LGKM0;
    READ_A(1, 1);
    PRIO1; MFMA_Q(0, 1); PRIO0;
    BARe;
    // ---- q6: (mh1, nh0); stage next B into buf1
    STAGE_B(1, kn1);
    BARw; LGKM0;
    PRIO1; MFMA_Q(1, 0); PRIO0;
    BARe;
    // ---- q7: (mh1, nh1); stage next A into buf1; land buf0; read-ahead next q0
    STAGE_A(1, kn1);
    VMC8;             // this-iter q2+q3 (tile 2i+2 -> buf0) landed
    BARw; LGKM0;
    READ_A(0, 0); READ_B(0, 0);
    PRIO1; MFMA_Q(1, 1); PRIO0;
    BARe;
  }

  // epilogue: D row = (lane>>4)*4 + r, col = lane&15
  const int row_h = (lane >> 4) * 4;
#pragma unroll
  for (int nf = 0; nf < 4; ++nf) {
    const int gcol = nblk * 256 + wn * 64 + nf * 16 + fr;
    const float bv = bias[gcol];
#pragma unroll
    for (int mf = 0; mf < 8; ++mf) {
      const int rbase = wm * 128 + mf * 16 + row_h;
#pragma unroll
      for (int r = 0; r < 4; ++r) {
        const int rit = rbase + r;
        float v = acc[mf][nf][r] + bv;
        if constexpr (MODE == 0) {
          outb[((size_t)mblk * 256 + rit) * ldout + coloff + gcol] = (bf16)v;
        } else if constexpr (MODE == 1) {
          outb[(size_t)(base + (long)mblk * 256 + rit) * ldout + gcol] =
              (bf16)fmaxf(v, 0.0f);
        } else {
          const long li = base + (long)mblk * 256 + rit;
          const float wgt = wgt_list[li];
          outb[(size_t)li * ldout + gcol] = (bf16)(wgt * v);
        }
      }
    }
  }
}

extern "C" void kernel_launch(void* const* d_in, const int* in_sizes, int n_in,
                              void* d_out, int out_size, void* d_ws, size_t ws_size,
                              hipStream_t stream) {
  const float* text  = (const float*)d_in[0];
  const float* image = (const float*)d_in[1];
  const float* noise = (const float*)d_in[2];
  const float* Wt    = (const float*)d_in[3];
  const float* bt    = (const float*)d_in[4];
  const float* Wi    = (const float*)d_in[5];
  const float* bi    = (const float*)d_in[6];
  const float* Wg    = (const float*)d_in[7];
  const float* bg    = (const float*)d_in[8];
  const float* W1    = (const float*)d_in[9];
  const float* b1    = (const float*)d_in[10];
  const float* W2    = (const float*)d_in[11];
  const float* b2    = (const float*)d_in[12];
  float* out = (float*)d_out;

  char* p = (char*)d_ws;
  auto alloc = [&](size_t bytes) {
    char* r = p; p += (bytes + 255) & ~(size_t)255; return r;
  };
  // union region: {text_b, image_b} (early) / pairbuf (late, after proj GEMMs)
  const size_t sz_text  = (size_t)BB * TD * 2;
  const size_t sz_texta = (sz_text + 255) & ~(size_t)255;
  const size_t sz_image = (size_t)BB * ID_ * 2;
  const size_t sz_pair  = (size_t)CAPT * OD * 2;
  size_t sz_u0 = sz_texta + sz_image;
  if (sz_pair > sz_u0) sz_u0 = sz_pair;
  char* u0 = alloc(sz_u0);
  bf16* text_b  = (bf16*)u0;
  bf16* image_b = (bf16*)(u0 + sz_texta);
  bf16* pairb   = (bf16*)u0;

  bf16*   WtT      = (bf16*)alloc((size_t)HID * TD * 2);
  bf16*   WiT      = (bf16*)alloc((size_t)HID * ID_ * 2);
  bf16*   W1T      = (bf16*)alloc((size_t)NE * HID * CB * 2);
  bf16*   W2T      = (bf16*)alloc((size_t)NE * OD * HID * 2);
  bf16*   combined = (bf16*)alloc((size_t)BB * CB * 2);
  bf16*   hbuf     = (bf16*)alloc((size_t)CAPT * HID * 2);
  double* WgF      = (double*)alloc((size_t)NE * GIN * 8);
  double* bgd      = (double*)alloc((size_t)NE * 8);
  Top2*   top2     = (Top2*)alloc((size_t)BB * sizeof(Top2));
  Slot2*  slots    = (Slot2*)alloc((size_t)BB * sizeof(Slot2));
  int*    counts   = (int*)alloc(NE * 4);
  int*    offsets  = (int*)alloc((NE + 1) * 4);
  int*    padded   = (int*)alloc(NE * 4);
  int*    pos      = (int*)alloc(NE * 4);
  int*    rows_list= (int*)alloc((size_t)CAPT * 4);
  float*  wgt_list = (float*)alloc((size_t)CAPT * 4);

  hipMemsetAsync(counts, 0, NE * 4, stream);

  transpose_cvt<<<dim3(HID / 64, TD / 64, 1),  256, 0, stream>>>(Wt, WtT, TD, HID);
  transpose_cvt<<<dim3(HID / 64, ID_ / 64, 1), 256, 0, stream>>>(Wi, WiT, ID_, HID);
  transpose_cvt<<<dim3(HID / 64, CB / 64, NE), 256, 0, stream>>>(W1, W1T, CB, HID);
  transpose_cvt<<<dim3(OD / 64, HID / 64, NE), 256, 0, stream>>>(W2, W2T, HID, OD);

  fuse_w<<<((GIN + 1) * NE + 255) / 256, 256, 0, stream>>>(
      Wt, Wi, Wg, bt, bi, bg, WgF, bgd);
  route1<<<BB / 64, 1024, 0, stream>>>(text, image, noise, WgF, bgd,
                                       text_b, image_b, top2, counts);
  scan_pad<<<1, 256, 0, stream>>>(counts, offsets, padded, pos, rows_list, wgt_list);
  route2<<<BB / 256, 256, 0, stream>>>(top2, pos, rows_list, wgt_list, slots);

  // proj: combined[:, :1024] = text @ Wt + bt ; combined[:, 1024:] = image @ Wi + bi
  // round-4 proven dispatch order: x = nblk, y = mblk
  gemm256<0><<<dim3(HID / 256, BB / 256, 1), 512, 0, stream>>>(
      text_b, WtT, bt, combined, nullptr, nullptr, nullptr, nullptr,
      TD, TD, TD, CB, 0);
  gemm256<0><<<dim3(HID / 256, BB / 256, 1), 512, 0, stream>>>(
      image_b, WiT, bi, combined, nullptr, nullptr, nullptr, nullptr,
      ID_, ID_, ID_, CB, HID);
  // expert FFN1 (gathered) -> h
  gemm256<1><<<dim3(HID / 256, 64, NE), 512, 0, stream>>>(
      combined, W1T, b1, hbuf, rows_list, nullptr, offsets, padded,
      CB, CB, CB, HID, 0);
  // expert FFN2 -> pair buffer (plain bf16 stores)
  gemm256<2><<<dim3(OD / 256, 64, NE), 512, 0, stream>>>(
      hbuf, W2T, b2, pairb, rows_list, wgt_list, offsets, padded,
      HID, HID, HID, OD, 0);
  // final: out[row] = pair[p0] + pair[p1]
  combine<<<BB, 256, 0, stream>>>(pairb, slots, out);
}

// Round 7
// 623.299 us; speedup vs baseline: 1.2261x; 1.0521x over previous
//
#include <hip/hip_runtime.h>
#include <stdint.h>
#include <stddef.h>

#define BB     16384
#define TD     768
#define ID_    1024
#define HID    1024
#define OD     1024
#define NE     8
#define CB     2048
#define CAPT   33792   // 32768 assignments + up to 8*127 pad (x128 padding)
#define GIN    1792    // TD + ID_

typedef __bf16 bf16;
typedef __bf16 bf16x4 __attribute__((ext_vector_type(4)));
typedef __bf16 bf16x8 __attribute__((ext_vector_type(8)));
typedef float  f32x4  __attribute__((ext_vector_type(4)));

struct Top2 { int e0, e1; float w0, w1; };
struct Slot2 { int p0, p1; };

__device__ __forceinline__ void gload16(void* lds, const void* g) {
#if __has_builtin(__builtin_amdgcn_global_load_lds)
  __builtin_amdgcn_global_load_lds(
      (const __attribute__((address_space(1))) void*)g,
      (__attribute__((address_space(3))) void*)lds, 16, 0, 0);
#else
  *(int4*)lds = *(const int4*)g;   // reg-staged fallback
#endif
}

// ---------------- transpose + f32->bf16 convert: src[R][C] f32 -> dst[C][R] bf16
__global__ void transpose_cvt(const float* __restrict__ src, bf16* __restrict__ dst,
                              int R, int C) {
  src += (size_t)blockIdx.z * R * C;
  dst += (size_t)blockIdx.z * R * C;
  __shared__ float tile[64][65];
  const int r0 = blockIdx.y * 64, c0 = blockIdx.x * 64;
  const int t = threadIdx.x;
#pragma unroll
  for (int i = 0; i < 16; ++i) {
    int e = i * 256 + t;
    int ii = e >> 6, jj = e & 63;
    tile[ii][jj] = src[(size_t)(r0 + ii) * C + (c0 + jj)];
  }
  __syncthreads();
#pragma unroll
  for (int i = 0; i < 16; ++i) {
    int e = i * 256 + t;
    int ii = e >> 6, jj = e & 63;
    dst[(size_t)(c0 + ii) * R + (r0 + jj)] = (bf16)tile[jj][ii];
  }
}

// ---------------- fused gating matrices in fp64, TRANSPOSED output [e][1792]
__global__ void fuse_w(const float* __restrict__ Wt, const float* __restrict__ Wi,
                       const float* __restrict__ Wg, const float* __restrict__ bt,
                       const float* __restrict__ bi, const float* __restrict__ bg,
                       double* __restrict__ WgF, double* __restrict__ bgd) {
  int o = blockIdx.x * blockDim.x + threadIdx.x;
  if (o >= (GIN + 1) * NE) return;
  int idx = o >> 3, e = o & 7;
  if (idx < TD) {
    double s = 0.0;
    for (int h = 0; h < HID; ++h)
      s += (double)Wt[(size_t)idx * HID + h] * (double)Wg[(size_t)h * NE + e];
    WgF[(size_t)e * GIN + idx] = s;
  } else if (idx < GIN) {
    int r = idx - TD;
    double s = 0.0;
    for (int h = 0; h < HID; ++h)
      s += (double)Wi[(size_t)r * HID + h] * (double)Wg[(size_t)(HID + h) * NE + e];
    WgF[(size_t)e * GIN + idx] = s;
  } else {
    double s = (double)bg[e];
    for (int h = 0; h < HID; ++h) {
      s += (double)bt[h] * (double)Wg[(size_t)h * NE + e];
      s += (double)bi[h] * (double)Wg[(size_t)(HID + h) * NE + e];
    }
    bgd[e] = s;
  }
}

// ---------------- routing pass 1: LDS-staged fp64 weights, 64 rows per block.
__global__ __launch_bounds__(1024)
void route1(const float* __restrict__ text, const float* __restrict__ image,
            const float* __restrict__ noise,
            const double* __restrict__ WgF, const double* __restrict__ bgd,
            bf16* __restrict__ text_b, bf16* __restrict__ image_b,
            Top2* __restrict__ top2, int* __restrict__ counts) {
  __shared__ double wg[NE * GIN];        // 112 KiB
  __shared__ int lcnt[NE];
  const int t = threadIdx.x;
  if (t < NE) lcnt[t] = 0;
  {
    const ulonglong2* src = (const ulonglong2*)WgF;
    ulonglong2* dst = (ulonglong2*)wg;
#pragma unroll
    for (int i = 0; i < (NE * GIN) / 2 / 1024; ++i)
      dst[i * 1024 + t] = src[i * 1024 + t];
  }
  __syncthreads();

  const int wave = t >> 6, lane = t & 63;
  const int row0 = blockIdx.x * 64;
#pragma unroll
  for (int rr = 0; rr < 4; ++rr) {
    const int row = row0 + wave + rr * 16;
    const float* tr = text + (size_t)row * TD;
    const float* ir = image + (size_t)row * ID_;
    float xv[28];
#pragma unroll
    for (int c = 0; c < 12; ++c) xv[c] = tr[lane + 64 * c];
#pragma unroll
    for (int c = 0; c < 16; ++c) xv[12 + c] = ir[lane + 64 * c];
    bf16* tb = text_b + (size_t)row * TD;
    bf16* ib = image_b + (size_t)row * ID_;
#pragma unroll
    for (int c = 0; c < 12; ++c) tb[lane + 64 * c] = (bf16)xv[c];
#pragma unroll
    for (int c = 0; c < 16; ++c) ib[lane + 64 * c] = (bf16)xv[12 + c];

    double acc[NE];
#pragma unroll
    for (int e = 0; e < NE; ++e) acc[e] = 0.0;
#pragma unroll
    for (int c = 0; c < 28; ++c) {
      const double vd = (double)xv[c];
      const int idx = lane + 64 * c;
#pragma unroll
      for (int e = 0; e < NE; ++e) acc[e] = fma(vd, wg[e * GIN + idx], acc[e]);
    }
#pragma unroll
    for (int off = 32; off > 0; off >>= 1) {
#pragma unroll
      for (int e = 0; e < NE; ++e) acc[e] += __shfl_down(acc[e], off);
    }
    if (lane == 0) {
      float nz[NE];
#pragma unroll
      for (int e = 0; e < NE; ++e)
        nz[e] = (float)(acc[e] + bgd[e]) + noise[(size_t)row * NE + e];
      int i0 = 0;
#pragma unroll
      for (int e = 1; e < NE; ++e) if (nz[e] > nz[i0]) i0 = e;
      int i1 = (i0 == 0) ? 1 : 0;
#pragma unroll
      for (int e = 0; e < NE; ++e) if (e != i0 && nz[e] > nz[i1]) i1 = e;
      float tt = expf(nz[i1] - nz[i0]);
      float w0 = 1.0f / (1.0f + tt);
      float w1 = tt / (1.0f + tt);
      Top2 rec; rec.e0 = i0; rec.e1 = i1; rec.w0 = w0; rec.w1 = w1;
      top2[row] = rec;
      atomicAdd(&lcnt[i0], 1);
      atomicAdd(&lcnt[i1], 1);
    }
  }
  __syncthreads();
  if (t < NE) atomicAdd(&counts[t], lcnt[t]);
}

// ---------------- scan: offsets (padded to x128), init pos
__global__ void scan_pad(const int* __restrict__ counts, int* __restrict__ offsets,
                         int* __restrict__ padded, int* __restrict__ pos,
                         int* __restrict__ rows_list, float* __restrict__ wgt_list) {
  __shared__ int s_off[NE], s_cnt[NE], s_pad[NE];
  if (threadIdx.x == 0) {
    int off = 0;
    for (int e = 0; e < NE; ++e) {
      int c = counts[e];
      int pd = (c + 127) & ~127;
      s_cnt[e] = c; s_pad[e] = pd; s_off[e] = off;
      offsets[e] = off; padded[e] = pd; pos[e] = off;
      off += pd;
    }
    offsets[NE] = off;
  }
  __syncthreads();
  for (int e = 0; e < NE; ++e) {
    for (int i = s_cnt[e] + threadIdx.x; i < s_pad[e]; i += blockDim.x) {
      rows_list[s_off[e] + i] = 0;
      wgt_list[s_off[e] + i] = 0.0f;
    }
  }
}

// ---------------- routing pass 2: block-aggregated scatter + slot map
__global__ void route2(const Top2* __restrict__ top2, int* __restrict__ pos,
                       int* __restrict__ rows_list, float* __restrict__ wgt_list,
                       Slot2* __restrict__ slots) {
  __shared__ int lcnt[NE], lbase[NE];
  if (threadIdx.x < NE) lcnt[threadIdx.x] = 0;
  __syncthreads();
  const int r = blockIdx.x * 256 + threadIdx.x;
  Top2 tt = top2[r];
  int s0 = atomicAdd(&lcnt[tt.e0], 1);
  int s1 = atomicAdd(&lcnt[tt.e1], 1);
  __syncthreads();
  if (threadIdx.x < NE)
    lbase[threadIdx.x] = atomicAdd(&pos[threadIdx.x], lcnt[threadIdx.x]);
  __syncthreads();
  int p0 = lbase[tt.e0] + s0;
  rows_list[p0] = r; wgt_list[p0] = tt.w0;
  int p1 = lbase[tt.e1] + s1;
  rows_list[p1] = r; wgt_list[p1] = tt.w1;
  Slot2 sl; sl.p0 = p0; sl.p1 = p1;
  slots[r] = sl;
}

// ---------------- final combine: out[row] = pair[p0] + pair[p1]
__global__ __launch_bounds__(256)
void combine(const bf16* __restrict__ pairb, const Slot2* __restrict__ slots,
             float* __restrict__ out) {
  const int row = blockIdx.x;
  const Slot2 s = slots[row];
  const int t = threadIdx.x;
  const bf16x4 a = *(const bf16x4*)(pairb + (size_t)s.p0 * OD + t * 4);
  const bf16x4 b = *(const bf16x4*)(pairb + (size_t)s.p1 * OD + t * 4);
  f32x4 r;
#pragma unroll
  for (int j = 0; j < 4; ++j) r[j] = (float)a[j] + (float)b[j];
  *(f32x4*)(out + (size_t)row * OD + t * 4) = r;
}

// ================= 128x128 BK=32 dbuf bf16 MFMA GEMM, 4 blocks/CU ================
// C[128x128 tile] = A[M][K] * BT[N][K]^T.  256 threads = 4 waves (2M x 2N),
// per-wave 64x64 output (acc[4][4]).  LDS 32 KiB (A,B double-buffered [2][128][32]).
// Occupancy play: __launch_bounds__(256,4) caps VGPR at 128 -> 4 blocks/CU
// (16 waves); independent blocks hide each other's stage latency (round-6 was
// latency-bound at 1 block/CU).  Counted vmcnt(4): next tile's 4 loads stay in
// flight across the barrier.  T2 source-pre-swizzle: granule col ^= row&3 at
// the global source; reads apply the same XOR -> balanced LDS bank groups.
// MODE 0: proj -> combined (bf16, +bias)
// MODE 1: expert FFN1 (gathered A rows) -> h (bf16, +b1, relu)
// MODE 2: expert FFN2 -> pairbuf (bf16, w*(acc+b2))

#define BARe  do { __builtin_amdgcn_s_barrier(); __builtin_amdgcn_sched_barrier(0); } while (0)
#define LGKM0 do { asm volatile("s_waitcnt lgkmcnt(0)" ::: "memory"); \
                   __builtin_amdgcn_sched_barrier(0); } while (0)
#define VMC4  asm volatile("s_waitcnt vmcnt(4)" ::: "memory")
#define PRIO1 __builtin_amdgcn_s_setprio(1)
#define PRIO0 __builtin_amdgcn_s_setprio(0)

#define STAGE128(BUF, KT) do { \
  _Pragma("unroll") for (int j_ = 0; j_ < 2; ++j_) { \
    gload16(&As[BUF][ldsoff[j_]], aptr[j_] + (size_t)(KT) * 32); \
    gload16(&Bs[BUF][ldsoff[j_]], bptr[j_] + (size_t)(KT) * 32); \
  } \
} while (0)

template<int MODE>
__global__ __launch_bounds__(256, 4)
void gemm128(const bf16* __restrict__ A, const bf16* __restrict__ BT,
             const float* __restrict__ bias, bf16* __restrict__ outb,
             const int* __restrict__ rows_list, const float* __restrict__ wgt_list,
             const int* __restrict__ offsets, const int* __restrict__ padded,
             int K, int lda, int ldb, int ldout, int coloff) {
  __shared__ bf16 As[2][128 * 32];
  __shared__ bf16 Bs[2][128 * 32];
  const int t = threadIdx.x;
  const int lane = t & 63, w = t >> 6;
  const int wm = w >> 1, wn = w & 1;
  const int mblk = blockIdx.y, nblk = blockIdx.x;

  long base = 0;
  if constexpr (MODE != 0) {
    const int e = blockIdx.z;
    if (mblk * 128 >= padded[e]) return;
    base = offsets[e];
    if constexpr (MODE == 1) { BT += (size_t)e * HID * CB; bias += e * HID; }
    else                     { BT += (size_t)e * OD * HID; bias += e * OD; }
  }

  // staging: load j covers granule g=j*256+t; row=g>>2; LDS dest linear (g*8);
  // global source col pre-swizzled: logical gcol = (g&3)^(row&3)
  const bf16* aptr[2]; const bf16* bptr[2]; int ldsoff[2];
#pragma unroll
  for (int j = 0; j < 2; ++j) {
    const int g = j * 256 + t, row = g >> 2;
    const int scol = ((g & 3) ^ (row & 3)) * 8;
    long ga;
    if constexpr (MODE == 1)      ga = rows_list[base + (long)mblk * 128 + row];
    else if constexpr (MODE == 2) ga = base + (long)mblk * 128 + row;
    else                          ga = (long)mblk * 128 + row;
    aptr[j] = A + ga * lda + scol;
    bptr[j] = BT + (size_t)(nblk * 128 + row) * ldb + scol;
    ldsoff[j] = g * 8;
  }

  // fragment reads: row = h*64 + f*16 + fr; row&3 = lane&3; k-octet o = lane>>4
  // physical granule = o ^ (lane&3)
  const int fr = lane & 15;
  const int swz = (((lane >> 4) ^ (lane & 3))) * 8;
  int a_off[4], b_off[4];
#pragma unroll
  for (int f = 0; f < 4; ++f) {
    a_off[f] = (wm * 64 + f * 16 + fr) * 32 + swz;
    b_off[f] = (wn * 64 + f * 16 + fr) * 32 + swz;
  }

  f32x4 acc[4][4];
#pragma unroll
  for (int i = 0; i < 4; ++i)
#pragma unroll
    for (int j = 0; j < 4; ++j)
#pragma unroll
      for (int r = 0; r < 4; ++r) acc[i][j][r] = 0.0f;

  const int NKT = K >> 5;

  STAGE128(0, 0);                       // tile 0 -> buf0 (4 loads in flight)
  for (int kt = 0; kt < NKT; ++kt) {
    const int kn = (kt + 1 < NKT) ? kt + 1 : 0;   // dummy at tail (never read)
    BARe;                               // prev iter's reads complete -> safe overwrite
    STAGE128((kt + 1) & 1, kn);         // 4 loads for next tile
    VMC4;                               // all-but-4 done => tile-kt loads landed
    BARe;                               // every wave's tile-kt data visible
    bf16x8 af[4], bfr[4];
#pragma unroll
    for (int f = 0; f < 4; ++f) af[f]  = *(const bf16x8*)(&As[kt & 1][a_off[f]]);
#pragma unroll
    for (int f = 0; f < 4; ++f) bfr[f] = *(const bf16x8*)(&Bs[kt & 1][b_off[f]]);
    LGKM0;
    PRIO1;
#pragma unroll
    for (int mf = 0; mf < 4; ++mf)
#pragma unroll
      for (int nf = 0; nf < 4; ++nf)
        acc[mf][nf] = __builtin_amdgcn_mfma_f32_16x16x32_bf16(af[mf], bfr[nf],
                                                              acc[mf][nf], 0, 0, 0);
    PRIO0;
  }

  // epilogue: D row = (lane>>4)*4 + r, col = lane&15
  const int row_h = (lane >> 4) * 4;
#pragma unroll
  for (int nf = 0; nf < 4; ++nf) {
    const int gcol = nblk * 128 + wn * 64 + nf * 16 + fr;
    const float bv = bias[gcol];
#pragma unroll
    for (int mf = 0; mf < 4; ++mf) {
      const int rbase = wm * 64 + mf * 16 + row_h;
#pragma unroll
      for (int r = 0; r < 4; ++r) {
        const int rit = rbase + r;
        float v = acc[mf][nf][r] + bv;
        if constexpr (MODE == 0) {
          outb[((size_t)mblk * 128 + rit) * ldout + coloff + gcol] = (bf16)v;
        } else if constexpr (MODE == 1) {
          outb[(size_t)(base + (long)mblk * 128 + rit) * ldout + gcol] =
              (bf16)fmaxf(v, 0.0f);
        } else {
          const long li = base + (long)mblk * 128 + rit;
          const float wgt = wgt_list[li];
          outb[(size_t)li * ldout + gcol] = (bf16)(wgt * v);
        }
      }
    }
  }
}

extern "C" void kernel_launch(void* const* d_in, const int* in_sizes, int n_in,
                              void* d_out, int out_size, void* d_ws, size_t ws_size,
                              hipStream_t stream) {
  const float* text  = (const float*)d_in[0];
  const float* image = (const float*)d_in[1];
  const float* noise = (const float*)d_in[2];
  const float* Wt    = (const float*)d_in[3];
  const float* bt    = (const float*)d_in[4];
  const float* Wi    = (const float*)d_in[5];
  const float* bi    = (const float*)d_in[6];
  const float* Wg    = (const float*)d_in[7];
  const float* bg    = (const float*)d_in[8];
  const float* W1    = (const float*)d_in[9];
  const float* b1    = (const float*)d_in[10];
  const float* W2    = (const float*)d_in[11];
  const float* b2    = (const float*)d_in[12];
  float* out = (float*)d_out;

  char* p = (char*)d_ws;
  auto alloc = [&](size_t bytes) {
    char* r = p; p += (bytes + 255) & ~(size_t)255; return r;
  };
  // union region: {text_b, image_b} (early) / pairbuf (late, after proj GEMMs)
  const size_t sz_text  = (size_t)BB * TD * 2;
  const size_t sz_texta = (sz_text + 255) & ~(size_t)255;
  const size_t sz_image = (size_t)BB * ID_ * 2;
  const size_t sz_pair  = (size_t)CAPT * OD * 2;
  size_t sz_u0 = sz_texta + sz_image;
  if (sz_pair > sz_u0) sz_u0 = sz_pair;
  char* u0 = alloc(sz_u0);
  bf16* text_b  = (bf16*)u0;
  bf16* image_b = (bf16*)(u0 + sz_texta);
  bf16* pairb   = (bf16*)u0;

  bf16*   WtT      = (bf16*)alloc((size_t)HID * TD * 2);
  bf16*   WiT      = (bf16*)alloc((size_t)HID * ID_ * 2);
  bf16*   W1T      = (bf16*)alloc((size_t)NE * HID * CB * 2);
  bf16*   W2T      = (bf16*)alloc((size_t)NE * OD * HID * 2);
  bf16*   combined = (bf16*)alloc((size_t)BB * CB * 2);
  bf16*   hbuf     = (bf16*)alloc((size_t)CAPT * HID * 2);
  double* WgF      = (double*)alloc((size_t)NE * GIN * 8);
  double* bgd      = (double*)alloc((size_t)NE * 8);
  Top2*   top2     = (Top2*)alloc((size_t)BB * sizeof(Top2));
  Slot2*  slots    = (Slot2*)alloc((size_t)BB * sizeof(Slot2));
  int*    counts   = (int*)alloc(NE * 4);
  int*    offsets  = (int*)alloc((NE + 1) * 4);
  int*    padded   = (int*)alloc(NE * 4);
  int*    pos      = (int*)alloc(NE * 4);
  int*    rows_list= (int*)alloc((size_t)CAPT * 4);
  float*  wgt_list = (float*)alloc((size_t)CAPT * 4);

  hipMemsetAsync(counts, 0, NE * 4, stream);

  transpose_cvt<<<dim3(HID / 64, TD / 64, 1),  256, 0, stream>>>(Wt, WtT, TD, HID);
  transpose_cvt<<<dim3(HID / 64, ID_ / 64, 1), 256, 0, stream>>>(Wi, WiT, ID_, HID);
  transpose_cvt<<<dim3(HID / 64, CB / 64, NE), 256, 0, stream>>>(W1, W1T, CB, HID);
  transpose_cvt<<<dim3(OD / 64, HID / 64, NE), 256, 0, stream>>>(W2, W2T, HID, OD);

  fuse_w<<<((GIN + 1) * NE + 255) / 256, 256, 0, stream>>>(
      Wt, Wi, Wg, bt, bi, bg, WgF, bgd);
  route1<<<BB / 64, 1024, 0, stream>>>(text, image, noise, WgF, bgd,
                                       text_b, image_b, top2, counts);
  scan_pad<<<1, 256, 0, stream>>>(counts, offsets, padded, pos, rows_list, wgt_list);
  route2<<<BB / 256, 256, 0, stream>>>(top2, pos, rows_list, wgt_list, slots);

  // proj: combined[:, :1024] = text @ Wt + bt ; combined[:, 1024:] = image @ Wi + bi
  // grid x = nblk (8): XCD = linear%8 = nblk -> B panel (512 KB) L2-resident/XCD
  gemm128<0><<<dim3(HID / 128, BB / 128, 1), 256, 0, stream>>>(
      text_b, WtT, bt, combined, nullptr, nullptr, nullptr, nullptr,
      TD, TD, TD, CB, 0);
  gemm128<0><<<dim3(HID / 128, BB / 128, 1), 256, 0, stream>>>(
      image_b, WiT, bi, combined, nullptr, nullptr, nullptr, nullptr,
      ID_, ID_, ID_, CB, HID);
  // expert FFN1 (gathered) -> h   (mblk grid covers worst-case 16384 rows/expert)
  gemm128<1><<<dim3(HID / 128, 128, NE), 256, 0, stream>>>(
      combined, W1T, b1, hbuf, rows_list, nullptr, offsets, padded,
      CB, CB, CB, HID, 0);
  // expert FFN2 -> pair buffer (plain bf16 stores)
  gemm128<2><<<dim3(OD / 128, 128, NE), 256, 0, stream>>>(
      hbuf, W2T, b2, pairb, rows_list, wgt_list, offsets, padded,
      HID, HID, HID, OD, 0);
  // final: out[row] = pair[p0] + pair[p1]
  combine<<<BB, 256, 0, stream>>>(pairb, slots, out);
}

// Round 8
// 574.207 us; speedup vs baseline: 1.3309x; 1.0855x over previous
//
#include <hip/hip_runtime.h>
#include <stdint.h>
#include <stddef.h>

#define BB     16384
#define TD     768
#define ID_    1024
#define HID    1024
#define OD     1024
#define NE     8
#define CB     2048
#define CAPT   33792   // 32768 assignments + up to 8*127 pad (x128 padding)
#define GIN    1792    // TD + ID_

typedef __bf16 bf16;
typedef __bf16 bf16x4 __attribute__((ext_vector_type(4)));
typedef __bf16 bf16x8 __attribute__((ext_vector_type(8)));
typedef float  f32x4  __attribute__((ext_vector_type(4)));

struct Top2 { int e0, e1; float w0, w1; };
struct Slot2 { int p0, p1; };

__device__ __forceinline__ void gload16(void* lds, const void* g) {
#if __has_builtin(__builtin_amdgcn_global_load_lds)
  __builtin_amdgcn_global_load_lds(
      (const __attribute__((address_space(1))) void*)g,
      (__attribute__((address_space(3))) void*)lds, 16, 0, 0);
#else
  *(int4*)lds = *(const int4*)g;   // reg-staged fallback
#endif
}

// ---------------- transpose + f32->bf16 convert: src[R][C] f32 -> dst[C][R] bf16
__global__ void transpose_cvt(const float* __restrict__ src, bf16* __restrict__ dst,
                              int R, int C) {
  src += (size_t)blockIdx.z * R * C;
  dst += (size_t)blockIdx.z * R * C;
  __shared__ float tile[64][65];
  const int r0 = blockIdx.y * 64, c0 = blockIdx.x * 64;
  const int t = threadIdx.x;
#pragma unroll
  for (int i = 0; i < 16; ++i) {
    int e = i * 256 + t;
    int ii = e >> 6, jj = e & 63;
    tile[ii][jj] = src[(size_t)(r0 + ii) * C + (c0 + jj)];
  }
  __syncthreads();
#pragma unroll
  for (int i = 0; i < 16; ++i) {
    int e = i * 256 + t;
    int ii = e >> 6, jj = e & 63;
    dst[(size_t)(c0 + ii) * R + (r0 + jj)] = (bf16)tile[jj][ii];
  }
}

// ---------------- fused gating matrices in fp64, TRANSPOSED output [e][1792]
__global__ void fuse_w(const float* __restrict__ Wt, const float* __restrict__ Wi,
                       const float* __restrict__ Wg, const float* __restrict__ bt,
                       const float* __restrict__ bi, const float* __restrict__ bg,
                       double* __restrict__ WgF, double* __restrict__ bgd) {
  int o = blockIdx.x * blockDim.x + threadIdx.x;
  if (o >= (GIN + 1) * NE) return;
  int idx = o >> 3, e = o & 7;
  if (idx < TD) {
    double s = 0.0;
    for (int h = 0; h < HID; ++h)
      s += (double)Wt[(size_t)idx * HID + h] * (double)Wg[(size_t)h * NE + e];
    WgF[(size_t)e * GIN + idx] = s;
  } else if (idx < GIN) {
    int r = idx - TD;
    double s = 0.0;
    for (int h = 0; h < HID; ++h)
      s += (double)Wi[(size_t)r * HID + h] * (double)Wg[(size_t)(HID + h) * NE + e];
    WgF[(size_t)e * GIN + idx] = s;
  } else {
    double s = (double)bg[e];
    for (int h = 0; h < HID; ++h) {
      s += (double)bt[h] * (double)Wg[(size_t)h * NE + e];
      s += (double)bi[h] * (double)Wg[(size_t)(HID + h) * NE + e];
    }
    bgd[e] = s;
  }
}

// ---------------- routing pass 1: LDS-staged fp64 weights, 64 rows per block.
__global__ __launch_bounds__(1024)
void route1(const float* __restrict__ text, const float* __restrict__ image,
            const float* __restrict__ noise,
            const double* __restrict__ WgF, const double* __restrict__ bgd,
            bf16* __restrict__ text_b, bf16* __restrict__ image_b,
            Top2* __restrict__ top2, int* __restrict__ counts) {
  __shared__ double wg[NE * GIN];        // 112 KiB
  __shared__ int lcnt[NE];
  const int t = threadIdx.x;
  if (t < NE) lcnt[t] = 0;
  {
    const ulonglong2* src = (const ulonglong2*)WgF;
    ulonglong2* dst = (ulonglong2*)wg;
#pragma unroll
    for (int i = 0; i < (NE * GIN) / 2 / 1024; ++i)
      dst[i * 1024 + t] = src[i * 1024 + t];
  }
  __syncthreads();

  const int wave = t >> 6, lane = t & 63;
  const int row0 = blockIdx.x * 64;
#pragma unroll
  for (int rr = 0; rr < 4; ++rr) {
    const int row = row0 + wave + rr * 16;
    const float* tr = text + (size_t)row * TD;
    const float* ir = image + (size_t)row * ID_;
    float xv[28];
#pragma unroll
    for (int c = 0; c < 12; ++c) xv[c] = tr[lane + 64 * c];
#pragma unroll
    for (int c = 0; c < 16; ++c) xv[12 + c] = ir[lane + 64 * c];
    bf16* tb = text_b + (size_t)row * TD;
    bf16* ib = image_b + (size_t)row * ID_;
#pragma unroll
    for (int c = 0; c < 12; ++c) tb[lane + 64 * c] = (bf16)xv[c];
#pragma unroll
    for (int c = 0; c < 16; ++c) ib[lane + 64 * c] = (bf16)xv[12 + c];

    double acc[NE];
#pragma unroll
    for (int e = 0; e < NE; ++e) acc[e] = 0.0;
#pragma unroll
    for (int c = 0; c < 28; ++c) {
      const double vd = (double)xv[c];
      const int idx = lane + 64 * c;
#pragma unroll
      for (int e = 0; e < NE; ++e) acc[e] = fma(vd, wg[e * GIN + idx], acc[e]);
    }
#pragma unroll
    for (int off = 32; off > 0; off >>= 1) {
#pragma unroll
      for (int e = 0; e < NE; ++e) acc[e] += __shfl_down(acc[e], off);
    }
    if (lane == 0) {
      float nz[NE];
#pragma unroll
      for (int e = 0; e < NE; ++e)
        nz[e] = (float)(acc[e] + bgd[e]) + noise[(size_t)row * NE + e];
      int i0 = 0;
#pragma unroll
      for (int e = 1; e < NE; ++e) if (nz[e] > nz[i0]) i0 = e;
      int i1 = (i0 == 0) ? 1 : 0;
#pragma unroll
      for (int e = 0; e < NE; ++e) if (e != i0 && nz[e] > nz[i1]) i1 = e;
      float tt = expf(nz[i1] - nz[i0]);
      float w0 = 1.0f / (1.0f + tt);
      float w1 = tt / (1.0f + tt);
      Top2 rec; rec.e0 = i0; rec.e1 = i1; rec.w0 = w0; rec.w1 = w1;
      top2[row] = rec;
      atomicAdd(&lcnt[i0], 1);
      atomicAdd(&lcnt[i1], 1);
    }
  }
  __syncthreads();
  if (t < NE) atomicAdd(&counts[t], lcnt[t]);
}

// ---------------- scan: offsets (padded to x128), init pos
__global__ void scan_pad(const int* __restrict__ counts, int* __restrict__ offsets,
                         int* __restrict__ padded, int* __restrict__ pos,
                         int* __restrict__ rows_list, float* __restrict__ wgt_list) {
  __shared__ int s_off[NE], s_cnt[NE], s_pad[NE];
  if (threadIdx.x == 0) {
    int off = 0;
    for (int e = 0; e < NE; ++e) {
      int c = counts[e];
      int pd = (c + 127) & ~127;
      s_cnt[e] = c; s_pad[e] = pd; s_off[e] = off;
      offsets[e] = off; padded[e] = pd; pos[e] = off;
      off += pd;
    }
    offsets[NE] = off;
  }
  __syncthreads();
  for (int e = 0; e < NE; ++e) {
    for (int i = s_cnt[e] + threadIdx.x; i < s_pad[e]; i += blockDim.x) {
      rows_list[s_off[e] + i] = 0;
      wgt_list[s_off[e] + i] = 0.0f;
    }
  }
}

// ---------------- routing pass 2: block-aggregated scatter + slot map
__global__ void route2(const Top2* __restrict__ top2, int* __restrict__ pos,
                       int* __restrict__ rows_list, float* __restrict__ wgt_list,
                       Slot2* __restrict__ slots) {
  __shared__ int lcnt[NE], lbase[NE];
  if (threadIdx.x < NE) lcnt[threadIdx.x] = 0;
  __syncthreads();
  const int r = blockIdx.x * 256 + threadIdx.x;
  Top2 tt = top2[r];
  int s0 = atomicAdd(&lcnt[tt.e0], 1);
  int s1 = atomicAdd(&lcnt[tt.e1], 1);
  __syncthreads();
  if (threadIdx.x < NE)
    lbase[threadIdx.x] = atomicAdd(&pos[threadIdx.x], lcnt[threadIdx.x]);
  __syncthreads();
  int p0 = lbase[tt.e0] + s0;
  rows_list[p0] = r; wgt_list[p0] = tt.w0;
  int p1 = lbase[tt.e1] + s1;
  rows_list[p1] = r; wgt_list[p1] = tt.w1;
  Slot2 sl; sl.p0 = p0; sl.p1 = p1;
  slots[r] = sl;
}

// ---------------- final combine: out[row] = pair[p0] + pair[p1]
__global__ __launch_bounds__(256)
void combine(const bf16* __restrict__ pairb, const Slot2* __restrict__ slots,
             float* __restrict__ out) {
  const int row = blockIdx.x;
  const Slot2 s = slots[row];
  const int t = threadIdx.x;
  const bf16x4 a = *(const bf16x4*)(pairb + (size_t)s.p0 * OD + t * 4);
  const bf16x4 b = *(const bf16x4*)(pairb + (size_t)s.p1 * OD + t * 4);
  f32x4 r;
#pragma unroll
  for (int j = 0; j < 4; ++j) r[j] = (float)a[j] + (float)b[j];
  *(f32x4*)(out + (size_t)row * OD + t * 4) = r;
}

// ================= 128x128 BK=32 dbuf bf16 MFMA GEMM, 4 blocks/CU ================
// C[128x128 tile] = A[M][K] * BT[N][K]^T.  256 threads = 4 waves (2M x 2N),
// per-wave 64x64 output (acc[4][4]).  LDS 32 KiB (A,B double-buffered).
// 1D grid, XCD-aware decode: xcd=bid&7; s=bid>>3; nblk=s&7; mblk=(s>>3)*8+xcd.
//   -> the 8 N-blocks sharing an A-tile are ids spaced 8 apart = SAME XCD,
//      launched adjacently => A-tile fetched once per XCD; XCDs own disjoint
//      A-tile sets; B panels shared via L3.  Requires M % 1024 == 0 (all true).
// Swizzle s(row)=(row>>1)&3 (fixed from r7's row&3): within a 16-lane b128
// phase, even rows now spread over all 4 granules -> 2-way only (free).
// MODE 0: proj -> combined (bf16, +bias)
// MODE 1: expert FFN1 (gathered A rows) -> h (bf16, +b1, relu)
// MODE 2: expert FFN2 -> pairbuf (bf16, w*(acc+b2))

#define BARe  do { __builtin_amdgcn_s_barrier(); __builtin_amdgcn_sched_barrier(0); } while (0)
#define LGKM0 do { asm volatile("s_waitcnt lgkmcnt(0)" ::: "memory"); \
                   __builtin_amdgcn_sched_barrier(0); } while (0)
#define VMC4  asm volatile("s_waitcnt vmcnt(4)" ::: "memory")
#define PRIO1 __builtin_amdgcn_s_setprio(1)
#define PRIO0 __builtin_amdgcn_s_setprio(0)

#define STAGE128(BUF, KT) do { \
  _Pragma("unroll") for (int j_ = 0; j_ < 2; ++j_) { \
    gload16(&As[BUF][ldsoff[j_]], aptr[j_] + (size_t)(KT) * 32); \
    gload16(&Bs[BUF][ldsoff[j_]], bptr[j_] + (size_t)(KT) * 32); \
  } \
} while (0)

template<int MODE>
__global__ __launch_bounds__(256, 4)
void gemm128(const bf16* __restrict__ A, const bf16* __restrict__ BT,
             const float* __restrict__ bias, bf16* __restrict__ outb,
             const int* __restrict__ rows_list, const float* __restrict__ wgt_list,
             const int* __restrict__ offsets, const int* __restrict__ padded,
             int K, int lda, int ldb, int ldout, int coloff) {
  __shared__ bf16 As[2][128 * 32];
  __shared__ bf16 Bs[2][128 * 32];
  const int t = threadIdx.x;
  const int lane = t & 63, w = t >> 6;
  const int wm = w >> 1, wn = w & 1;
  // XCD-aware decode (8 N-tiles in every GEMM here)
  const int bid = blockIdx.x;
  const int xcd = bid & 7, sdec = bid >> 3;
  const int nblk = sdec & 7, mblk = (sdec >> 3) * 8 + xcd;

  long base = 0;
  if constexpr (MODE != 0) {
    const int e = blockIdx.z;
    if (mblk * 128 >= padded[e]) return;
    base = offsets[e];
    if constexpr (MODE == 1) { BT += (size_t)e * HID * CB; bias += e * HID; }
    else                     { BT += (size_t)e * OD * HID; bias += e * OD; }
  }

  // staging: load j covers granule g=j*256+t; row=g>>2; LDS dest linear (g*16B);
  // global source col pre-swizzled: logical gcol = (g&3) ^ ((row>>1)&3)
  const bf16* aptr[2]; const bf16* bptr[2]; int ldsoff[2];
#pragma unroll
  for (int j = 0; j < 2; ++j) {
    const int g = j * 256 + t, row = g >> 2;
    const int scol = ((g & 3) ^ ((row >> 1) & 3)) * 8;
    long ga;
    if constexpr (MODE == 1)      ga = rows_list[base + (long)mblk * 128 + row];
    else if constexpr (MODE == 2) ga = base + (long)mblk * 128 + row;
    else                          ga = (long)mblk * 128 + row;
    aptr[j] = A + ga * lda + scol;
    bptr[j] = BT + (size_t)(nblk * 128 + row) * ldb + scol;
    ldsoff[j] = g * 8;
  }

  // fragment reads: row = base16 + fr (base16 % 16 == 0) -> (row>>1)&3 = (fr>>1)&3
  const int fr = lane & 15;
  const int swz = ((lane >> 4) ^ ((fr >> 1) & 3)) * 8;
  int a_off[4], b_off[4];
#pragma unroll
  for (int f = 0; f < 4; ++f) {
    a_off[f] = (wm * 64 + f * 16 + fr) * 32 + swz;
    b_off[f] = (wn * 64 + f * 16 + fr) * 32 + swz;
  }

  f32x4 acc[4][4];
#pragma unroll
  for (int i = 0; i < 4; ++i)
#pragma unroll
    for (int j = 0; j < 4; ++j)
#pragma unroll
      for (int r = 0; r < 4; ++r) acc[i][j][r] = 0.0f;

  const int NKT = K >> 5;

  STAGE128(0, 0);                       // tile 0 -> buf0 (4 loads in flight)
  for (int kt = 0; kt < NKT; ++kt) {
    const int kn = (kt + 1 < NKT) ? kt + 1 : 0;   // dummy at tail (never read)
    BARe;                               // prev iter's reads complete -> safe overwrite
    STAGE128((kt + 1) & 1, kn);         // 4 loads for next tile
    VMC4;                               // all-but-4 done => tile-kt loads landed
    BARe;                               // every wave's tile-kt data visible
    bf16x8 af[4], bfr[4];
#pragma unroll
    for (int f = 0; f < 4; ++f) af[f]  = *(const bf16x8*)(&As[kt & 1][a_off[f]]);
#pragma unroll
    for (int f = 0; f < 4; ++f) bfr[f] = *(const bf16x8*)(&Bs[kt & 1][b_off[f]]);
    LGKM0;
    PRIO1;
#pragma unroll
    for (int mf = 0; mf < 4; ++mf)
#pragma unroll
      for (int nf = 0; nf < 4; ++nf)
        acc[mf][nf] = __builtin_amdgcn_mfma_f32_16x16x32_bf16(af[mf], bfr[nf],
                                                              acc[mf][nf], 0, 0, 0);
    PRIO0;
  }

  // epilogue: D row = (lane>>4)*4 + r, col = lane&15
  const int row_h = (lane >> 4) * 4;
#pragma unroll
  for (int nf = 0; nf < 4; ++nf) {
    const int gcol = nblk * 128 + wn * 64 + nf * 16 + fr;
    const float bv = bias[gcol];
#pragma unroll
    for (int mf = 0; mf < 4; ++mf) {
      const int rbase = wm * 64 + mf * 16 + row_h;
#pragma unroll
      for (int r = 0; r < 4; ++r) {
        const int rit = rbase + r;
        float v = acc[mf][nf][r] + bv;
        if constexpr (MODE == 0) {
          outb[((size_t)mblk * 128 + rit) * ldout + coloff + gcol] = (bf16)v;
        } else if constexpr (MODE == 1) {
          outb[(size_t)(base + (long)mblk * 128 + rit) * ldout + gcol] =
              (bf16)fmaxf(v, 0.0f);
        } else {
          const long li = base + (long)mblk * 128 + rit;
          const float wgt = wgt_list[li];
          outb[(size_t)li * ldout + gcol] = (bf16)(wgt * v);
        }
      }
    }
  }
}

extern "C" void kernel_launch(void* const* d_in, const int* in_sizes, int n_in,
                              void* d_out, int out_size, void* d_ws, size_t ws_size,
                              hipStream_t stream) {
  const float* text  = (const float*)d_in[0];
  const float* image = (const float*)d_in[1];
  const float* noise = (const float*)d_in[2];
  const float* Wt    = (const float*)d_in[3];
  const float* bt    = (const float*)d_in[4];
  const float* Wi    = (const float*)d_in[5];
  const float* bi    = (const float*)d_in[6];
  const float* Wg    = (const float*)d_in[7];
  const float* bg    = (const float*)d_in[8];
  const float* W1    = (const float*)d_in[9];
  const float* b1    = (const float*)d_in[10];
  const float* W2    = (const float*)d_in[11];
  const float* b2    = (const float*)d_in[12];
  float* out = (float*)d_out;

  char* p = (char*)d_ws;
  auto alloc = [&](size_t bytes) {
    char* r = p; p += (bytes + 255) & ~(size_t)255; return r;
  };
  // union region: {text_b, image_b} (early) / pairbuf (late, after proj GEMMs)
  const size_t sz_text  = (size_t)BB * TD * 2;
  const size_t sz_texta = (sz_text + 255) & ~(size_t)255;
  const size_t sz_image = (size_t)BB * ID_ * 2;
  const size_t sz_pair  = (size_t)CAPT * OD * 2;
  size_t sz_u0 = sz_texta + sz_image;
  if (sz_pair > sz_u0) sz_u0 = sz_pair;
  char* u0 = alloc(sz_u0);
  bf16* text_b  = (bf16*)u0;
  bf16* image_b = (bf16*)(u0 + sz_texta);
  bf16* pairb   = (bf16*)u0;

  bf16*   WtT      = (bf16*)alloc((size_t)HID * TD * 2);
  bf16*   WiT      = (bf16*)alloc((size_t)HID * ID_ * 2);
  bf16*   W1T      = (bf16*)alloc((size_t)NE * HID * CB * 2);
  bf16*   W2T      = (bf16*)alloc((size_t)NE * OD * HID * 2);
  bf16*   combined = (bf16*)alloc((size_t)BB * CB * 2);
  bf16*   hbuf     = (bf16*)alloc((size_t)CAPT * HID * 2);
  double* WgF      = (double*)alloc((size_t)NE * GIN * 8);
  double* bgd      = (double*)alloc((size_t)NE * 8);
  Top2*   top2     = (Top2*)alloc((size_t)BB * sizeof(Top2));
  Slot2*  slots    = (Slot2*)alloc((size_t)BB * sizeof(Slot2));
  int*    counts   = (int*)alloc(NE * 4);
  int*    offsets  = (int*)alloc((NE + 1) * 4);
  int*    padded   = (int*)alloc(NE * 4);
  int*    pos      = (int*)alloc(NE * 4);
  int*    rows_list= (int*)alloc((size_t)CAPT * 4);
  float*  wgt_list = (float*)alloc((size_t)CAPT * 4);

  hipMemsetAsync(counts, 0, NE * 4, stream);

  transpose_cvt<<<dim3(HID / 64, TD / 64, 1),  256, 0, stream>>>(Wt, WtT, TD, HID);
  transpose_cvt<<<dim3(HID / 64, ID_ / 64, 1), 256, 0, stream>>>(Wi, WiT, ID_, HID);
  transpose_cvt<<<dim3(HID / 64, CB / 64, NE), 256, 0, stream>>>(W1, W1T, CB, HID);
  transpose_cvt<<<dim3(OD / 64, HID / 64, NE), 256, 0, stream>>>(W2, W2T, HID, OD);

  fuse_w<<<((GIN + 1) * NE + 255) / 256, 256, 0, stream>>>(
      Wt, Wi, Wg, bt, bi, bg, WgF, bgd);
  route1<<<BB / 64, 1024, 0, stream>>>(text, image, noise, WgF, bgd,
                                       text_b, image_b, top2, counts);
  scan_pad<<<1, 256, 0, stream>>>(counts, offsets, padded, pos, rows_list, wgt_list);
  route2<<<BB / 256, 256, 0, stream>>>(top2, pos, rows_list, wgt_list, slots);

  // proj: combined[:, :1024] = text @ Wt + bt ; combined[:, 1024:] = image @ Wi + bi
  // 1D grid: 128 mblk x 8 nblk = 1024 blocks, XCD-decoded in-kernel
  gemm128<0><<<dim3(1024, 1, 1), 256, 0, stream>>>(
      text_b, WtT, bt, combined, nullptr, nullptr, nullptr, nullptr,
      TD, TD, TD, CB, 0);
  gemm128<0><<<dim3(1024, 1, 1), 256, 0, stream>>>(
      image_b, WiT, bi, combined, nullptr, nullptr, nullptr, nullptr,
      ID_, ID_, ID_, CB, HID);
  // expert FFN1 (gathered) -> h   (128 mblk covers worst-case 16384 rows/expert)
  gemm128<1><<<dim3(1024, 1, NE), 256, 0, stream>>>(
      combined, W1T, b1, hbuf, rows_list, nullptr, offsets, padded,
      CB, CB, CB, HID, 0);
  // expert FFN2 -> pair buffer (plain bf16 stores)
  gemm128<2><<<dim3(1024, 1, NE), 256, 0, stream>>>(
      hbuf, W2T, b2, pairb, rows_list, wgt_list, offsets, padded,
      HID, HID, HID, OD, 0);
  // final: out[row] = pair[p0] + pair[p1]
  combine<<<BB, 256, 0, stream>>>(pairb, slots, out);
}